// Round 9
// baseline (360.133 us; speedup 1.0000x reference)
//
#include <hip/hip_runtime.h>

// Problem constants
#define HD    16
#define DH    128
#define BB    2
#define SS    2048
#define DM    2048
#define NQKV  6144   // 3*HD*DH
#define MTOT  4096   // BB*SS

typedef short   bfx8  __attribute__((ext_vector_type(8)));   // 8 bf16 (4 VGPRs)
typedef float   f32x4 __attribute__((ext_vector_type(4)));

__device__ __forceinline__ unsigned short f2bf(float f) {
  union { float f; unsigned int u; } c; c.f = f;
  unsigned int u = c.u + 0x7FFFu + ((c.u >> 16) & 1u);
  return (unsigned short)(u >> 16);
}

__device__ __forceinline__ void gload_lds16(const unsigned short* g, unsigned short* l) {
  __builtin_amdgcn_global_load_lds(
      (const __attribute__((address_space(1))) unsigned int*)g,
      (__attribute__((address_space(3))) unsigned int*)l, 16, 0, 0);
}

// counted-vmcnt sync: fence compiler (memory clobber + sched_barrier), raw barrier (no drain)
#define SYNCV(N) do {                                     \
    asm volatile("s_waitcnt vmcnt(" #N ")" ::: "memory"); \
    __builtin_amdgcn_sched_barrier(0);                    \
    __builtin_amdgcn_s_barrier();                         \
    __builtin_amdgcn_sched_barrier(0);                    \
  } while (0)

// ---------------- f32 -> bf16 cast ----------------
__global__ __launch_bounds__(256) void f32_to_bf16_k(const float* __restrict__ in,
                                                     unsigned short* __restrict__ out, int n4) {
  int i = (blockIdx.x * 256 + threadIdx.x);
  if (i >= n4) return;
  const float4 v = *(const float4*)(in + (size_t)i * 4);
  ushort4 o;
  o.x = f2bf(v.x); o.y = f2bf(v.y); o.z = f2bf(v.z); o.w = f2bf(v.w);
  *(ushort4*)(out + (size_t)i * 4) = o;
}

// ---------------- f32 [R][C] -> bf16 [C][R] transpose ----------------
__global__ __launch_bounds__(256) void transpose_f32_bf16_k(const float* __restrict__ in,
                                                            unsigned short* __restrict__ out,
                                                            int R, int C) {
  __shared__ float t[32][33];
  const int c0 = blockIdx.x * 32, r0 = blockIdx.y * 32;
  const int tx = threadIdx.x & 31, ty = threadIdx.x >> 5;  // 32 x 8
#pragma unroll
  for (int i = 0; i < 4; i++) {
    int r = r0 + ty + i * 8;
    t[ty + i * 8][tx] = in[(size_t)r * C + c0 + tx];
  }
  __syncthreads();
#pragma unroll
  for (int i = 0; i < 4; i++) {
    int c = c0 + ty + i * 8;
    out[(size_t)c * R + r0 + tx] = f2bf(t[tx][ty + i * 8]);
  }
}

// ---------------- deep-pipeline bf16 GEMM: C = A[M][K] * Bt[N][K]^T ----------------
// 128x128 tile, BK=32, 4 waves (2x2 of 64x64), ring-4 LDS (64 KB), counted vmcnt,
// one raw barrier per K-tile, setprio around MFMA cluster, XCD-bijective grid remap.
// QKV==0: C0 = f32 [M][ldc]. QKV==1: split epilogue -> Qg/Kg [b][h][s][d], Vg [b][h][d][s].
template <int QKV>
__global__ __launch_bounds__(256, 2) void gemm_deep_k(const unsigned short* __restrict__ A,
                                                      const unsigned short* __restrict__ Bt,
                                                      void* __restrict__ C0, void* __restrict__ C1,
                                                      void* __restrict__ C2, int K, int ldc,
                                                      int nwg8) {
  __shared__ __align__(16) unsigned short As[4][128 * 32];
  __shared__ __align__(16) unsigned short Bs[4][128 * 32];
  const int tid = threadIdx.x;
  const int lane = tid & 63, wid = tid >> 6;
  const int wr = wid >> 1, wc = wid & 1;
  const int cbase = lane & 15, rgrp = lane >> 4;
  // XCD-bijective remap (nwg % 8 == 0), m-fast: each XCD owns a contiguous n-range
  const int bid = (int)blockIdx.x;
  const int id = (bid & 7) * nwg8 + (bid >> 3);
  const int mb = id & 31, nb = id >> 5;      // M/128 == 32 for all our GEMMs
  const size_t m0 = (size_t)mb * 128, n0 = (size_t)nb * 128;
  const int nkt = K >> 5;

#define STAGE_G(kt_) do {                                                          \
    const int s_ = (kt_) & 3;                                                      \
    for (int i_ = 0; i_ < 2; i_++) {                                               \
      int idx_ = i_ * 256 + tid;                                                   \
      int row_ = idx_ >> 2, cb_ = idx_ & 3;                                        \
      gload_lds16(A + (m0 + row_) * K + ((kt_) * 32 + cb_ * 8), &As[s_][idx_ * 8]);\
      gload_lds16(Bt + (n0 + row_) * K + ((kt_) * 32 + cb_ * 8), &Bs[s_][idx_ * 8]);\
    } } while (0)

  f32x4 acc[4][4];
  const f32x4 z = {0.f, 0.f, 0.f, 0.f};
#pragma unroll
  for (int mf = 0; mf < 4; mf++)
#pragma unroll
    for (int nf = 0; nf < 4; nf++) acc[mf][nf] = z;

#define COMPUTE_G(kt_) do {                                                        \
    const int s_ = (kt_) & 3;                                                      \
    bfx8 af_[4], bf_[4];                                                           \
    for (int mf = 0; mf < 4; mf++)                                                 \
      af_[mf] = *(const bfx8*)(&As[s_][(wr * 64 + mf * 16 + cbase) * 32 + rgrp * 8]);\
    for (int nf = 0; nf < 4; nf++)                                                 \
      bf_[nf] = *(const bfx8*)(&Bs[s_][(wc * 64 + nf * 16 + cbase) * 32 + rgrp * 8]);\
    __builtin_amdgcn_s_setprio(1);                                                 \
    for (int mf = 0; mf < 4; mf++)                                                 \
      for (int nf = 0; nf < 4; nf++)                                               \
        acc[mf][nf] = __builtin_amdgcn_mfma_f32_16x16x32_bf16(af_[mf], bf_[nf], acc[mf][nf], 0, 0, 0);\
    __builtin_amdgcn_s_setprio(0);                                                 \
  } while (0)

  // prologue: fill 3 ring slots (12 loads); wait until tile 0 landed (<=8 outstanding)
  STAGE_G(0); STAGE_G(1); STAGE_G(2);
  SYNCV(8);

#pragma unroll 1
  for (int kt = 0; kt < nkt - 3; ++kt) {
    STAGE_G(kt + 3);       // writes slot (kt+3)&3 == (kt-1)&3: readers finished last iter
    COMPUTE_G(kt);
    SYNCV(8);              // tiles kt+2,kt+3 (8 loads) stay in flight; kt+1 guaranteed landed
  }
  COMPUTE_G(nkt - 3); SYNCV(4);
  COMPUTE_G(nkt - 2); SYNCV(0);
  COMPUTE_G(nkt - 1);

#undef STAGE_G
#undef COMPUTE_G

  if (QKV) {
    // nb in [0,48): h = nb/3, t = nb%3
    const int h = nb / 3, t = nb - 3 * (nb / 3);
#pragma unroll
    for (int mf = 0; mf < 4; mf++)
#pragma unroll
      for (int nf = 0; nf < 4; nf++) {
        const int d = wc * 64 + nf * 16 + cbase;
        const int row0 = (int)m0 + wr * 64 + mf * 16 + rgrp * 4;
        const int bb = row0 >> 11;        // same batch for r=0..3
        const int s0 = row0 & 2047;
        if (t == 2) {
          ushort4 v;
          v.x = f2bf(acc[mf][nf][0]); v.y = f2bf(acc[mf][nf][1]);
          v.z = f2bf(acc[mf][nf][2]); v.w = f2bf(acc[mf][nf][3]);
          unsigned short* dstV = (unsigned short*)C2;
          *(ushort4*)(dstV + ((size_t)(bb * HD + h) * DH + d) * SS + s0) = v;
        } else {
          unsigned short* dst = (unsigned short*)(t == 0 ? C0 : C1);
#pragma unroll
          for (int r = 0; r < 4; r++)
            dst[((size_t)(bb * HD + h) * SS + s0 + r) * DH + d] = f2bf(acc[mf][nf][r]);
        }
      }
  } else {
    float* C = (float*)C0;
#pragma unroll
    for (int mf = 0; mf < 4; mf++)
#pragma unroll
      for (int nf = 0; nf < 4; nf++)
#pragma unroll
        for (int r = 0; r < 4; r++) {
          size_t row = m0 + wr * 64 + mf * 16 + rgrp * 4 + r;
          size_t col = n0 + wc * 64 + nf * 16 + cbase;
          C[row * ldc + col] = acc[mf][nf][r];
        }
  }
}

// ---------------- flash attention (bf16) ----------------
// 4 waves, 64 q-rows per block (16 per wave), KVBLK=64, XOR-swizzled LDS.
// Grid: 1024 blocks 1-D. bh=(bid%8)*4+(bid/8)%4 (4 bh per XCD -> K/V L2-resident),
// qt = 31 - bid/32 (heavy blocks dispatched first).
// K/V^T staged via global_load_lds with PRE-SWIZZLED global source (linear LDS dest);
// swizzle: byte_in_row ^= (row&7)<<4. All LDS reads apply the same XOR -> <=2-way conflicts.
__global__ __launch_bounds__(256) void attn_fwd_k(const unsigned short* __restrict__ Qg,
                                                  const unsigned short* __restrict__ Kg,
                                                  const unsigned short* __restrict__ Vg,
                                                  unsigned short* __restrict__ ao) {
  __shared__ __align__(16) unsigned short Klds[64 * 128];   // 16 KB, row=kv, 256 B/row
  __shared__ __align__(16) unsigned short Vt[128 * 64];     // 16 KB, row=d,  128 B/row
  __shared__ __align__(16) unsigned short Plds[4][16 * 64]; //  8 KB, per-wave, 128 B/row
  const int tid = threadIdx.x;
  const int lane = tid & 63, wid = tid >> 6;
  const int cbase = lane & 15, rgrp = lane >> 4;

  const int bid = (int)blockIdx.x;
  const int bh = (bid & 7) * 4 + ((bid >> 3) & 3);
  const int qt = 31 - (bid >> 5);
  const int b = bh >> 4, h = bh & 15;
  const int qbase = qt * 64;

  const unsigned short* qp0 = Qg + (size_t)(b * HD + h) * SS * DH;
  const unsigned short* kp  = Kg + (size_t)(b * HD + h) * SS * DH;
  const unsigned short* vp  = Vg + (size_t)(b * HD + h) * DH * SS;
  const float scale = 0.08838834764831845f;  // 1/sqrt(128)
  const f32x4 z = {0.f, 0.f, 0.f, 0.f};

  bfx8 qf[4];
  {
    const unsigned short* qp = qp0 + (size_t)(qbase + wid * 16 + cbase) * DH;
#pragma unroll
    for (int ks = 0; ks < 4; ks++) qf[ks] = *(const bfx8*)(qp + ks * 32 + rgrp * 8);
  }

  float m_run[4], l_run[4];
  f32x4 o[8];
#pragma unroll
  for (int r = 0; r < 4; r++) { m_run[r] = -1e30f; l_run[r] = 0.f; }
#pragma unroll
  for (int mb = 0; mb < 8; mb++) o[mb] = z;

  const int ntiles = qt + 1;
  for (int t = 0; t < ntiles; ++t) {
    const int kvb = t * 64;
    // stage K [64 kv][128 d]: linear dest, pre-swizzled source
#pragma unroll
    for (int i = 0; i < 4; i++) {
      int idx = i * 256 + tid;
      int r = idx >> 4, bofs = (idx & 15) * 16;
      gload_lds16(kp + (size_t)(kvb + r) * DH + ((bofs ^ ((r & 7) << 4)) >> 1),
                  Klds + idx * 8);
    }
    // stage V^T [128 d][64 kv]: linear dest, pre-swizzled source
#pragma unroll
    for (int i = 0; i < 4; i++) {
      int idx = i * 256 + tid;
      int d = idx >> 3, bofs = (idx & 7) * 16;
      gload_lds16(vp + (size_t)d * SS + kvb + ((bofs ^ ((d & 7) << 4)) >> 1),
                  Vt + idx * 8);
    }
    __syncthreads();

    // S = Q K^T  (four 16x16 kv-col tiles)
    f32x4 s[4];
#pragma unroll
    for (int nf = 0; nf < 4; nf++) s[nf] = z;
#pragma unroll
    for (int nf = 0; nf < 4; nf++) {
      const int row = nf * 16 + cbase;
#pragma unroll
      for (int ks = 0; ks < 4; ks++) {
        bfx8 kf = *(const bfx8*)(Klds + ((row * 256 + ((ks * 64 + rgrp * 16) ^ ((row & 7) << 4))) >> 1));
        s[nf] = __builtin_amdgcn_mfma_f32_16x16x32_bf16(qf[ks], kf, s[nf], 0, 0, 0);
      }
    }

    // scale + causal mask (diagonal tile only) + online softmax
    const bool diag = (t == ntiles - 1);
    float p[4][4], alpha[4];
#pragma unroll
    for (int r = 0; r < 4; r++) {
      const int qi = qbase + wid * 16 + rgrp * 4 + r;
      float sv[4];
#pragma unroll
      for (int nf = 0; nf < 4; nf++) sv[nf] = s[nf][r] * scale;
      if (diag) {
#pragma unroll
        for (int nf = 0; nf < 4; nf++)
          if (kvb + nf * 16 + cbase > qi) sv[nf] = -1e30f;
      }
      float tm = fmaxf(fmaxf(sv[0], sv[1]), fmaxf(sv[2], sv[3]));
#pragma unroll
      for (int off = 1; off < 16; off <<= 1) tm = fmaxf(tm, __shfl_xor(tm, off));
      const float mnew = fmaxf(m_run[r], tm);
      float rs = 0.f;
#pragma unroll
      for (int nf = 0; nf < 4; nf++) { p[nf][r] = __expf(sv[nf] - mnew); rs += p[nf][r]; }
#pragma unroll
      for (int off = 1; off < 16; off <<= 1) rs += __shfl_xor(rs, off);
      alpha[r] = __expf(m_run[r] - mnew);
      l_run[r] = l_run[r] * alpha[r] + rs;
      m_run[r] = mnew;
    }
#pragma unroll
    for (int mb = 0; mb < 8; mb++)
#pragma unroll
      for (int r = 0; r < 4; r++) o[mb][r] *= alpha[r];

    // P (C-layout) -> swizzled LDS -> A-fragment layout
#pragma unroll
    for (int nf = 0; nf < 4; nf++)
#pragma unroll
      for (int r = 0; r < 4; r++) {
        const int row = rgrp * 4 + r;
        Plds[wid][(row * 128 + ((nf * 32 + cbase * 2) ^ ((row & 7) << 4))) >> 1] = f2bf(p[nf][r]);
      }
    bfx8 pf[2];
#pragma unroll
    for (int k2 = 0; k2 < 2; k2++)
      pf[k2] = *(const bfx8*)(&Plds[wid][(cbase * 128 + ((k2 * 64 + rgrp * 16) ^ ((cbase & 7) << 4))) >> 1]);

    // O += P * V  (two k-slices of 32)
#pragma unroll
    for (int mb = 0; mb < 8; mb++) {
      const int d = mb * 16 + cbase;
#pragma unroll
      for (int k2 = 0; k2 < 2; k2++) {
        bfx8 vf = *(const bfx8*)(Vt + ((d * 128 + ((k2 * 64 + rgrp * 16) ^ ((d & 7) << 4))) >> 1));
        o[mb] = __builtin_amdgcn_mfma_f32_16x16x32_bf16(pf[k2], vf, o[mb], 0, 0, 0);
      }
    }
    __syncthreads();
  }

  // normalize + write AO [b*S + q][h*128 + d] (bf16)
  float rinv[4];
#pragma unroll
  for (int r = 0; r < 4; r++) rinv[r] = 1.0f / l_run[r];
  const int qrow0 = qbase + wid * 16 + rgrp * 4;
#pragma unroll
  for (int mb = 0; mb < 8; mb++)
#pragma unroll
    for (int r = 0; r < 4; r++) {
      size_t idx = ((size_t)(b * SS + qrow0 + r)) * (size_t)DM + h * DH + mb * 16 + cbase;
      ao[idx] = f2bf(o[mb][r] * rinv[r]);
    }
}

extern "C" void kernel_launch(void* const* d_in, const int* in_sizes, int n_in,
                              void* d_out, int out_size, void* d_ws, size_t ws_size,
                              hipStream_t stream) {
  (void)in_sizes; (void)n_in; (void)out_size; (void)ws_size;
  const float* x     = (const float*)d_in[0];
  const float* w_in  = (const float*)d_in[1];
  const float* w_out = (const float*)d_in[2];
  float* out = (float*)d_out;

  char* ws = (char*)d_ws;
  unsigned short* Xb  = (unsigned short*)(ws);                     // 16 MB  [4096][2048]
  unsigned short* Wit = (unsigned short*)(ws + (16ull << 20));     // 24 MB  [6144][2048]
  unsigned short* Wot = (unsigned short*)(ws + (40ull << 20));     //  8 MB  [2048][2048]
  unsigned short* Qg  = (unsigned short*)(ws + (48ull << 20));     // 16 MB  [b][h][s][d]
  unsigned short* Kg  = (unsigned short*)(ws + (64ull << 20));     // 16 MB  [b][h][s][d]
  unsigned short* Vg  = (unsigned short*)(ws + (80ull << 20));     // 16 MB  [b][h][d][s]
  unsigned short* AO  = (unsigned short*)(ws + (96ull << 20));     // 16 MB  [4096][2048]

  // x -> bf16
  f32_to_bf16_k<<<MTOT * DM / 4 / 256, 256, 0, stream>>>(x, Xb, MTOT * DM / 4);
  // w_in [2048][6144] -> Wit [6144][2048] bf16
  transpose_f32_bf16_k<<<dim3(NQKV / 32, DM / 32), 256, 0, stream>>>(w_in, Wit, DM, NQKV);
  // w_out [2048][2048] -> Wot transposed bf16
  transpose_f32_bf16_k<<<dim3(DM / 32, DM / 32), 256, 0, stream>>>(w_out, Wot, DM, DM);
  // QKV projection (deep pipeline) -> Qg, Kg, Vg(transposed); grid 32x48 = 1536, nwg/8 = 192
  gemm_deep_k<1><<<1536, 256, 0, stream>>>(Xb, Wit, Qg, Kg, Vg, DM, 0, 192);
  // attention -> AO
  attn_fwd_k<<<1024, 256, 0, stream>>>(Qg, Kg, Vg, AO);
  // out = AO @ Wot^T (f32, deep pipeline); grid 32x16 = 512, nwg/8 = 64
  gemm_deep_k<0><<<512, 256, 0, stream>>>(AO, Wot, out, nullptr, nullptr, DM, DM, 64);
}